// Round 11
// baseline (3842.124 us; speedup 1.0000x reference)
//
#include <hip/hip_runtime.h>
#include <hip/hip_bf16.h>

#define NNODES 100000
#define NEDGES 1600000
#define CH 128
#define OUTC 40
#define BN_EPS 1e-5f
#define NBUCK 782              // ceil(NNODES/128)
#define FILL_BLOCKS 128
#define EPB (NEDGES / FILL_BLOCKS)  // 12500

typedef __attribute__((ext_vector_type(8))) short s8v;    // 8 bf16 (4 VGPR)
typedef __attribute__((ext_vector_type(4))) float f32x4;  // MFMA acc

__device__ inline unsigned short f2bf_rn(float f) {
    unsigned u = __float_as_uint(f);
    return (unsigned short)((u + 0x7FFFu + ((u >> 16) & 1u)) >> 16);
}
__device__ inline float bf2f(unsigned short b) {
    return __uint_as_float((unsigned)b << 16);
}

// ---------------- degree histogram ----------------
__global__ void k_deg(const int* __restrict__ dst, int* __restrict__ deg) {
    int e = blockIdx.x * blockDim.x + threadIdx.x;
    if (e < NEDGES) atomicAdd(&deg[dst[e]], 1);
}

// ---------------- exclusive scan (3-phase) ----------------
__global__ void k_scan1(const int* __restrict__ deg, int* __restrict__ row_ptr,
                        int* __restrict__ blkSums, float* __restrict__ inv_deg) {
    __shared__ int sd[256];
    int base = blockIdx.x * 1024 + threadIdx.x * 4;
    int t[4];
#pragma unroll
    for (int j = 0; j < 4; ++j) {
        int i = base + j;
        t[j] = (i < NNODES) ? deg[i] : 0;
        if (i < NNODES) inv_deg[i] = 1.0f / fmaxf((float)t[j], 1.0f);
    }
    int tsum = t[0] + t[1] + t[2] + t[3];
    sd[threadIdx.x] = tsum;
    __syncthreads();
    for (int off = 1; off < 256; off <<= 1) {
        int v = (threadIdx.x >= off) ? sd[threadIdx.x - off] : 0;
        __syncthreads();
        sd[threadIdx.x] += v;
        __syncthreads();
    }
    int run = sd[threadIdx.x] - tsum;
#pragma unroll
    for (int j = 0; j < 4; ++j) {
        int i = base + j;
        if (i < NNODES) row_ptr[i] = run;
        run += t[j];
    }
    if (threadIdx.x == 255) blkSums[blockIdx.x] = sd[255];
}

// parallel scan of <=128 block sums (was a 1-thread serial loop: ~98 dependent
// global RMWs @ ~900cyc — tens of µs hidden cost)
__global__ void k_scan2(int* __restrict__ blkSums, int nb) {
    __shared__ int sd[128];
    int t = threadIdx.x;
    int v = (t < nb) ? blkSums[t] : 0;
    sd[t] = v;
    __syncthreads();
    for (int off = 1; off < 128; off <<= 1) {
        int u = (t >= off) ? sd[t - off] : 0;
        __syncthreads();
        sd[t] += u;
        __syncthreads();
    }
    if (t < nb) blkSums[t] = sd[t] - v;  // exclusive
}

__global__ void k_scan3(int* __restrict__ row_ptr, const int* __restrict__ blkSums) {
    int i = blockIdx.x * blockDim.x + threadIdx.x;
    if (i < NNODES) row_ptr[i] += blkSums[i >> 10];
    if (i == 0) row_ptr[NNODES] = NEDGES;
}

__global__ void k_binit(const int* __restrict__ row_ptr, int* __restrict__ bcur) {
    int b = blockIdx.x * 256 + threadIdx.x;
    if (b < NBUCK) bcur[b] = row_ptr[b << 7];
}

// ---------------- bucketed edge partition (replaces per-node scatter) -------
// Bucket = dst>>7 (128 nodes). LDS histogram -> one global atomicAdd per
// (block,bucket) run reservation -> contiguous ~128B run writes. Kills the
// 16x write amplification of the old 4B/node scatter (105MB -> ~25MB HBM).
__global__ __launch_bounds__(256) void k_fillb(const int* __restrict__ src,
                                               const int* __restrict__ dst,
                                               int* __restrict__ bcur,
                                               int2* __restrict__ tmp) {
    __shared__ int h[NBUCK];
    int tid = threadIdx.x;
    int e0 = blockIdx.x * EPB;
    for (int i = tid; i < NBUCK; i += 256) h[i] = 0;
    __syncthreads();
    for (int e = e0 + tid; e < e0 + EPB; e += 256)
        atomicAdd(&h[dst[e] >> 7], 1);
    __syncthreads();
    for (int b = tid; b < NBUCK; b += 256) {
        int c = h[b];
        h[b] = c ? atomicAdd(&bcur[b], c) : 0;
    }
    __syncthreads();
    for (int e = e0 + tid; e < e0 + EPB; e += 256) {
        int d = dst[e];
        int pos = atomicAdd(&h[d >> 7], 1);
        tmp[pos] = make_int2(src[e], d);
    }
}

// ---------------- W prep: transpose + hi/lo bf16 split (once per call) ----------------
__global__ void k_prepw(const float* __restrict__ Wl0, const float* __restrict__ Wr0,
                        const float* __restrict__ Wl1, const float* __restrict__ Wr1,
                        const float* __restrict__ Wl2, const float* __restrict__ Wr2,
                        short* __restrict__ wt) {
    int gid = blockIdx.x * 256 + threadIdx.x;
    const float* W;
    int col, k, base, halfsz;
    float val;
    if (gid < 65536) {
        int w = gid >> 14;
        int r = gid & 16383;
        col = r >> 7; k = r & 127;
        W = (w == 0) ? Wl0 : (w == 1) ? Wr0 : (w == 2) ? Wl1 : Wr1;
        val = W[k * 128 + col];
        base = w * 32768; halfsz = 16384;
    } else if (gid < 77824) {
        int r2 = gid - 65536;
        int w = r2 / 6144;
        int r = r2 - w * 6144;
        col = r >> 7; k = r & 127;
        W = w ? Wr2 : Wl2;
        val = (col < OUTC) ? W[k * OUTC + col] : 0.f;
        base = 131072 + w * 12288; halfsz = 6144;
    } else {
        return;
    }
    unsigned short hi = f2bf_rn(val);
    unsigned short lo = f2bf_rn(val - bf2f(hi));
    int idx = col * 128 + k;
    wt[base + idx] = (short)hi;
    wt[base + halfsz + idx] = (short)lo;
}

// ---------------- MFMA dual GEMM (bf16x3): yl = f(H)@Wl ; yr = f(H)@Wr + b ----
template <int WRW, int WCW, int RF, int CF, int WCOLS, int NCR, int LSZ, bool BN_A>
__global__ __launch_bounds__(256, 1) void k_gemm_mfma(
    const float* __restrict__ H,
    const short* __restrict__ WtL, const short* __restrict__ WtR,
    const float* __restrict__ bias,
    const float* __restrict__ bnscale, const float* __restrict__ bnshift,
    float* __restrict__ yl, float* __restrict__ yr) {
    __shared__ short A_hi[128 * 128];
    __shared__ short A_lo[128 * 128];
    __shared__ short B_hi[WCOLS * 128];
    __shared__ short B_lo[WCOLS * 128];

    int tid = threadIdx.x;
    int row0 = blockIdx.x * 128;

#pragma unroll
    for (int i = 0; i < 8; ++i) {
        int c = tid + 256 * i;
        int r = c >> 4;
        int k0 = (c & 15) << 3;
        int gr = row0 + r;
        float f[8];
        if (gr < NNODES) {
            float4 v0 = *(const float4*)&H[(size_t)gr * CH + k0];
            float4 v1 = *(const float4*)&H[(size_t)gr * CH + k0 + 4];
            f[0] = v0.x; f[1] = v0.y; f[2] = v0.z; f[3] = v0.w;
            f[4] = v1.x; f[5] = v1.y; f[6] = v1.z; f[7] = v1.w;
        } else {
#pragma unroll
            for (int j = 0; j < 8; ++j) f[j] = 0.f;
        }
        if (BN_A) {
            float4 s0 = *(const float4*)&bnscale[k0];
            float4 s1 = *(const float4*)&bnscale[k0 + 4];
            float4 h0 = *(const float4*)&bnshift[k0];
            float4 h1 = *(const float4*)&bnshift[k0 + 4];
            f[0] = fmaxf(fmaf(f[0], s0.x, h0.x), 0.f);
            f[1] = fmaxf(fmaf(f[1], s0.y, h0.y), 0.f);
            f[2] = fmaxf(fmaf(f[2], s0.z, h0.z), 0.f);
            f[3] = fmaxf(fmaf(f[3], s0.w, h0.w), 0.f);
            f[4] = fmaxf(fmaf(f[4], s1.x, h1.x), 0.f);
            f[5] = fmaxf(fmaf(f[5], s1.y, h1.y), 0.f);
            f[6] = fmaxf(fmaf(f[6], s1.z, h1.z), 0.f);
            f[7] = fmaxf(fmaf(f[7], s1.w, h1.w), 0.f);
        }
        s8v hi8, lo8;
#pragma unroll
        for (int j = 0; j < 8; ++j) {
            unsigned short h = f2bf_rn(f[j]);
            hi8[j] = (short)h;
            lo8[j] = (short)f2bf_rn(f[j] - bf2f(h));
        }
        int e = ((r << 7) + k0) ^ ((r & 7) << 3);
        *(s8v*)&A_hi[e] = hi8;
        *(s8v*)&A_lo[e] = lo8;
    }

    int lane = tid & 63;
    int wid = tid >> 6;
    int wr = wid / WCW, wc = wid % WCW;
    int l15 = lane & 15, kb = lane >> 4;
    int rowbase = wr * RF * 16;
    int colbase = wc * CF * 16;

    for (int half = 0; half < 2; ++half) {
        if (half == 1) __syncthreads();
        const short* Wt = half ? WtR : WtL;
        constexpr int WCHUNK = WCOLS * 16;
#pragma unroll
        for (int i = 0; i < (WCHUNK + 255) / 256; ++i) {
            int c = tid + 256 * i;
            if (c < WCHUNK) {
                int col = c >> 4;
                int k0 = (c & 15) << 3;
                s8v hi8 = *(const s8v*)&Wt[col * 128 + k0];
                s8v lo8 = *(const s8v*)&Wt[LSZ + col * 128 + k0];
                int e = ((col << 7) + k0) ^ ((col & 7) << 3);
                *(s8v*)&B_hi[e] = hi8;
                *(s8v*)&B_lo[e] = lo8;
            }
        }
        __syncthreads();

        f32x4 acc[RF][CF];
#pragma unroll
        for (int i = 0; i < RF; ++i)
#pragma unroll
            for (int j = 0; j < CF; ++j) acc[i][j] = (f32x4){0.f, 0.f, 0.f, 0.f};

#pragma unroll
        for (int ks = 0; ks < 4; ++ks) {
            s8v ah[RF], al[RF];
#pragma unroll
            for (int rf = 0; rf < RF; ++rf) {
                int r = rowbase + rf * 16 + l15;
                int e = ((r << 7) + ks * 32 + (kb << 3)) ^ ((r & 7) << 3);
                ah[rf] = *(const s8v*)&A_hi[e];
                al[rf] = *(const s8v*)&A_lo[e];
            }
#pragma unroll
            for (int cf = 0; cf < CF; ++cf) {
                int cc = colbase + cf * 16 + l15;
                int e = ((cc << 7) + ks * 32 + (kb << 3)) ^ ((cc & 7) << 3);
                s8v bh = *(const s8v*)&B_hi[e];
                s8v bl = *(const s8v*)&B_lo[e];
#pragma unroll
                for (int rf = 0; rf < RF; ++rf) {
                    acc[rf][cf] = __builtin_amdgcn_mfma_f32_16x16x32_bf16(ah[rf], bh, acc[rf][cf], 0, 0, 0);
                    acc[rf][cf] = __builtin_amdgcn_mfma_f32_16x16x32_bf16(al[rf], bh, acc[rf][cf], 0, 0, 0);
                    acc[rf][cf] = __builtin_amdgcn_mfma_f32_16x16x32_bf16(ah[rf], bl, acc[rf][cf], 0, 0, 0);
                }
            }
        }

        float* Y = half ? yr : yl;
#pragma unroll
        for (int cf = 0; cf < CF; ++cf) {
            int gcol = colbase + cf * 16 + l15;
            float bb = 0.f;
            if (half == 1 && gcol < NCR) bb = bias[gcol];
#pragma unroll
            for (int rf = 0; rf < RF; ++rf) {
#pragma unroll
                for (int r = 0; r < 4; ++r) {
                    int grow = row0 + rowbase + rf * 16 + (lane >> 4) * 4 + r;
                    if (grow < NNODES && gcol < NCR)
                        Y[(size_t)grow * NCR + gcol] = acc[rf][cf][r] + bb;
                }
            }
        }
    }
}

// ---------------- bucketed combine (NC=128): z[n] += invdeg*sum yl[src] ------
// block = bucket of 128 dst nodes; LDS acc rows; ds_add_f32 (2 lanes/bank=free).
__global__ __launch_bounds__(256) void k_combineb128(
    const float* __restrict__ yl, const int2* __restrict__ tmp,
    const int* __restrict__ row_ptr, const float* __restrict__ inv_deg,
    float* __restrict__ z) {
    __shared__ float acc[128 * 128];  // 64KB
    int tid = threadIdx.x;
    int node0 = blockIdx.x << 7;
    for (int i = tid; i < 128 * 32; i += 256)
        ((float4*)acc)[i] = make_float4(0.f, 0.f, 0.f, 0.f);
    int s0 = row_ptr[node0];
    int s1 = row_ptr[min(node0 + 128, NNODES)];
    __syncthreads();
    int lane = tid & 63, wid = tid >> 6;
    int cnt = s1 - s0;
    int es = s0 + (int)(((long)cnt * wid) >> 2);
    int ee = s0 + (int)(((long)cnt * (wid + 1)) >> 2);
    int e = es;
    for (; e + 4 <= ee; e += 4) {
        int2 d0 = tmp[e], d1 = tmp[e + 1], d2 = tmp[e + 2], d3 = tmp[e + 3];
        float vx0 = yl[(size_t)d0.x * 128 + lane];
        float vy0 = yl[(size_t)d0.x * 128 + 64 + lane];
        float vx1 = yl[(size_t)d1.x * 128 + lane];
        float vy1 = yl[(size_t)d1.x * 128 + 64 + lane];
        float vx2 = yl[(size_t)d2.x * 128 + lane];
        float vy2 = yl[(size_t)d2.x * 128 + 64 + lane];
        float vx3 = yl[(size_t)d3.x * 128 + lane];
        float vy3 = yl[(size_t)d3.x * 128 + 64 + lane];
        atomicAdd(&acc[((d0.y & 127) << 7) + lane], vx0);
        atomicAdd(&acc[((d0.y & 127) << 7) + 64 + lane], vy0);
        atomicAdd(&acc[((d1.y & 127) << 7) + lane], vx1);
        atomicAdd(&acc[((d1.y & 127) << 7) + 64 + lane], vy1);
        atomicAdd(&acc[((d2.y & 127) << 7) + lane], vx2);
        atomicAdd(&acc[((d2.y & 127) << 7) + 64 + lane], vy2);
        atomicAdd(&acc[((d3.y & 127) << 7) + lane], vx3);
        atomicAdd(&acc[((d3.y & 127) << 7) + 64 + lane], vy3);
    }
    for (; e < ee; ++e) {
        int2 d = tmp[e];
        float vx = yl[(size_t)d.x * 128 + lane];
        float vy = yl[(size_t)d.x * 128 + 64 + lane];
        atomicAdd(&acc[((d.y & 127) << 7) + lane], vx);
        atomicAdd(&acc[((d.y & 127) << 7) + 64 + lane], vy);
    }
    __syncthreads();
    int nn = min(128, NNODES - node0);
    for (int i = tid; i < nn * 32; i += 256) {
        int row = i >> 5, c4 = (i & 31) << 2;
        float4 a = *(float4*)&acc[(row << 7) + c4];
        float w = inv_deg[node0 + row];
        float4 zr = *(float4*)&z[(((size_t)(node0 + row)) << 7) + c4];
        zr.x += a.x * w; zr.y += a.y * w; zr.z += a.z * w; zr.w += a.w * w;
        *(float4*)&z[(((size_t)(node0 + row)) << 7) + c4] = zr;
    }
}

// ---------------- bucketed combine (NC=40) + log_softmax -> out --------------
__global__ __launch_bounds__(256) void k_combineb40(
    const float* __restrict__ yl, const int2* __restrict__ tmp,
    const int* __restrict__ row_ptr, const float* __restrict__ inv_deg,
    const float* __restrict__ yr, float* __restrict__ out) {
    __shared__ float acc[128 * 40];  // 20KB
    int tid = threadIdx.x;
    int node0 = blockIdx.x << 7;
    for (int i = tid; i < 128 * 10; i += 256)
        ((float4*)acc)[i] = make_float4(0.f, 0.f, 0.f, 0.f);
    int s0 = row_ptr[node0];
    int s1 = row_ptr[min(node0 + 128, NNODES)];
    __syncthreads();
    int lane = tid & 63, wid = tid >> 6;
    bool act = lane < 20;
    int cnt = s1 - s0;
    int es = s0 + (int)(((long)cnt * wid) >> 2);
    int ee = s0 + (int)(((long)cnt * (wid + 1)) >> 2);
    for (int e = es; e < ee; ++e) {
        int2 d = tmp[e];
        if (act) {
            float2 v = *(const float2*)&yl[(size_t)d.x * OUTC + lane * 2];
            atomicAdd(&acc[(d.y & 127) * OUTC + lane * 2], v.x);
            atomicAdd(&acc[(d.y & 127) * OUTC + lane * 2 + 1], v.y);
        }
    }
    __syncthreads();
    for (int i = wid; i < 128; i += 4) {
        int node = node0 + i;
        if (node >= NNODES) break;
        float zx = 0.f, zy = 0.f;
        if (act) {
            float w = inv_deg[node];
            float2 r = *(const float2*)&yr[(size_t)node * OUTC + lane * 2];
            zx = acc[i * OUTC + lane * 2] * w + r.x;
            zy = acc[i * OUTC + lane * 2 + 1] * w + r.y;
        }
        float m = act ? fmaxf(zx, zy) : -INFINITY;
#pragma unroll
        for (int off = 1; off <= 16; off <<= 1) m = fmaxf(m, __shfl_xor(m, off));
        float se = act ? (expf(zx - m) + expf(zy - m)) : 0.f;
#pragma unroll
        for (int off = 1; off <= 16; off <<= 1) se += __shfl_xor(se, off);
        float lse = m + logf(se);
        if (act) {
            float2 o = make_float2(zx - lse, zy - lse);
            *(float2*)&out[(size_t)node * OUTC + lane * 2] = o;
        }
    }
}

// ---------------- BN batch stats (sum, sumsq per channel) ----------------
__global__ void k_stats(const float* __restrict__ h, float* __restrict__ sums) {
    __shared__ float ls[256], ls2[256];
    int c = threadIdx.x & 127;
    int half = threadIdx.x >> 7;
    float s = 0.f, s2 = 0.f;
    for (int r = blockIdx.x * 2 + half; r < NNODES; r += gridDim.x * 2) {
        float v = h[(size_t)r * CH + c];
        s += v; s2 += v * v;
    }
    ls[threadIdx.x] = s; ls2[threadIdx.x] = s2;
    __syncthreads();
    if (half == 0) {
        atomicAdd(&sums[c], ls[c] + ls[c + 128]);
        atomicAdd(&sums[CH + c], ls2[c] + ls2[c + 128]);
    }
}

__global__ void k_bn_finalize(const float* __restrict__ sums, const float* __restrict__ g,
                              const float* __restrict__ be, float* __restrict__ scale,
                              float* __restrict__ shift) {
    int c = threadIdx.x;
    if (c < CH) {
        float mean = sums[c] * (1.0f / NNODES);
        float var = sums[128 + c] * (1.0f / NNODES) - mean * mean;
        float sc = g[c] * rsqrtf(var + BN_EPS);
        scale[c] = sc;
        shift[c] = be[c] - mean * sc;
    }
}

extern "C" void kernel_launch(void* const* d_in, const int* in_sizes, int n_in,
                              void* d_out, int out_size, void* d_ws, size_t ws_size,
                              hipStream_t stream) {
    const float* x   = (const float*)d_in[0];
    const int* esrc  = (const int*)d_in[1];
    const int* edst  = (const int*)d_in[2];
    const float* W_l0 = (const float*)d_in[3];
    const float* b_l0 = (const float*)d_in[4];
    const float* W_r0 = (const float*)d_in[5];
    const float* g0   = (const float*)d_in[6];
    const float* be0  = (const float*)d_in[7];
    const float* W_l1 = (const float*)d_in[8];
    const float* b_l1 = (const float*)d_in[9];
    const float* W_r1 = (const float*)d_in[10];
    const float* g1   = (const float*)d_in[11];
    const float* be1  = (const float*)d_in[12];
    const float* W_l2 = (const float*)d_in[13];
    const float* b_l2 = (const float*)d_in[14];
    const float* W_r2 = (const float*)d_in[15];
    float* out = (float*)d_out;

    char* w = (char*)d_ws;
    size_t o = 0;
    auto nxt = [&](size_t b) { void* p = w + o; o = (o + b + 511) & ~(size_t)511; return p; };
    int* deg      = (int*)nxt((size_t)NNODES * 4);
    int* row_ptr  = (int*)nxt((size_t)(NNODES + 1) * 4);
    float* invdeg = (float*)nxt((size_t)NNODES * 4);
    int* blkSums  = (int*)nxt(128 * 4);
    int* bcur     = (int*)nxt(NBUCK * 4);
    float* sums   = (float*)nxt(512 * 4);
    float* scsh   = (float*)nxt(512 * 4);
    short* wtbuf  = (short*)nxt(155648 * 2);   // prepped W^T hi/lo bf16
    int2* tmp     = (int2*)nxt((size_t)NEDGES * 8);
    float* ylbuf  = (float*)nxt((size_t)NNODES * CH * 4);
    float* zA     = (float*)nxt((size_t)NNODES * CH * 4);  // z0, later yr2
    float* zB     = (float*)nxt((size_t)NNODES * CH * 4);  // z1
    float* sums0 = sums, *sums1 = sums + 256;
    float* scale0 = scsh, *shift0 = scsh + 128, *scale1 = scsh + 256, *shift1 = scsh + 384;

    const short* wtL0 = wtbuf;
    const short* wtR0 = wtbuf + 32768;
    const short* wtL1 = wtbuf + 65536;
    const short* wtR1 = wtbuf + 98304;
    const short* wtL2 = wtbuf + 131072;
    const short* wtR2 = wtbuf + 143360;

    hipMemsetAsync(deg, 0, (size_t)NNODES * 4, stream);
    hipMemsetAsync(sums, 0, 512 * 4, stream);

    const int EB = (NEDGES + 255) / 256;
    const int SCAN_B = (NNODES + 1023) / 1024;  // 98
    const int NB = (NNODES + 255) / 256;
    const int GEMM_B = (NNODES + 127) / 128;  // 782

    // W prep + CSR(bucket) build
    k_prepw<<<304, 256, 0, stream>>>(W_l0, W_r0, W_l1, W_r1, W_l2, W_r2, wtbuf);
    k_deg<<<EB, 256, 0, stream>>>(edst, deg);
    k_scan1<<<SCAN_B, 256, 0, stream>>>(deg, row_ptr, blkSums, invdeg);
    k_scan2<<<1, 128, 0, stream>>>(blkSums, SCAN_B);
    k_scan3<<<NB, 256, 0, stream>>>(row_ptr, blkSums);
    k_binit<<<4, 256, 0, stream>>>(row_ptr, bcur);
    k_fillb<<<FILL_BLOCKS, 256, 0, stream>>>(esrc, edst, bcur, tmp);

    // layer 0
    k_gemm_mfma<2, 2, 4, 4, 128, 128, 16384, false><<<GEMM_B, 256, 0, stream>>>(
        x, wtL0, wtR0, b_l0, nullptr, nullptr, ylbuf, zA);
    k_combineb128<<<NBUCK, 256, 0, stream>>>(ylbuf, tmp, row_ptr, invdeg, zA);
    k_stats<<<256, 256, 0, stream>>>(zA, sums0);
    k_bn_finalize<<<1, 128, 0, stream>>>(sums0, g0, be0, scale0, shift0);

    // layer 1
    k_gemm_mfma<2, 2, 4, 4, 128, 128, 16384, true><<<GEMM_B, 256, 0, stream>>>(
        zA, wtL1, wtR1, b_l1, scale0, shift0, ylbuf, zB);
    k_combineb128<<<NBUCK, 256, 0, stream>>>(ylbuf, tmp, row_ptr, invdeg, zB);
    k_stats<<<256, 256, 0, stream>>>(zB, sums1);
    k_bn_finalize<<<1, 128, 0, stream>>>(sums1, g1, be1, scale1, shift1);

    // layer 2
    k_gemm_mfma<4, 1, 2, 3, 48, 40, 6144, true><<<GEMM_B, 256, 0, stream>>>(
        zB, wtL2, wtR2, b_l2, scale1, shift1, ylbuf, zA);
    k_combineb40<<<NBUCK, 256, 0, stream>>>(ylbuf, tmp, row_ptr, invdeg, zA, out);
}